// Round 3
// baseline (796.742 us; speedup 1.0000x reference)
//
#include <hip/hip_runtime.h>
#include <hip/hip_bf16.h>
#include <stdint.h>

#define B_ 128
#define T_ 255
#define N_ 256
#define H_ 256

// k4 U-matrix split: pairs [0,92) in VGPRs, [92,128) in LDS
#define RP_ 92
#define LP_ 36

typedef _Float16 f16;
typedef _Float16 f16x2 __attribute__((ext_vector_type(2)));
typedef _Float16 f16x8 __attribute__((ext_vector_type(8)));
typedef float f32x4 __attribute__((ext_vector_type(4)));

static __device__ __forceinline__ float fdot2(uint32_t h, uint32_t u, float acc) {
#if __has_builtin(__builtin_amdgcn_fdot2)
  return __builtin_amdgcn_fdot2(__builtin_bit_cast(f16x2, h),
                                __builtin_bit_cast(f16x2, u), acc, false);
#else
  f16x2 a = __builtin_bit_cast(f16x2, h);
  f16x2 b = __builtin_bit_cast(f16x2, u);
  return acc + (float)a.x * (float)b.x + (float)a.y * (float)b.y;
#endif
}

// ---------------- K0: pack W_lstm (transposed) and U_lstm (k-pair packed) to f16
__global__ __launch_bounds__(256) void k0_pack(const float* __restrict__ Wl,
                                               const float* __restrict__ Ul,
                                               uint32_t* __restrict__ u_packed,
                                               f16* __restrict__ wt) {
  int idx = blockIdx.x * 256 + threadIdx.x;
  if (idx < 256 * 1024) {              // wt[n][k] = Wl[k][n]
    int n = idx >> 8, k = idx & 255;
    wt[n * 256 + k] = (f16)Wl[k * 1024 + n];
  }
  if (idx < 128 * 1024) {              // u_packed[p][c] = (U[2p][c], U[2p+1][c])
    int p = idx >> 10, c = idx & 1023;
    f16x2 v;
    v.x = (f16)Ul[(2 * p) * 1024 + c];
    v.y = (f16)Ul[(2 * p + 1) * 1024 + c];
    u_packed[idx] = __builtin_bit_cast(uint32_t, v);
  }
}

// ---------------- K1: alpha[b][n] = softmax_n( sum_t X[b,t,n] * Wa[512+t] )
__global__ __launch_bounds__(256) void k1_alpha(const float* __restrict__ X,
                                                const float* __restrict__ Wa,
                                                float* __restrict__ alpha) {
  int b = blockIdx.x, n = threadIdx.x;
  const float* xb = X + b * (T_ * N_) + n;
  float a0 = 0.f, a1 = 0.f, a2 = 0.f, a3 = 0.f;
  int t = 0;
  for (; t + 4 <= T_; t += 4) {
    a0 += xb[(t + 0) * N_] * Wa[512 + t + 0];
    a1 += xb[(t + 1) * N_] * Wa[512 + t + 1];
    a2 += xb[(t + 2) * N_] * Wa[512 + t + 2];
    a3 += xb[(t + 3) * N_] * Wa[512 + t + 3];
  }
  for (; t < T_; ++t) a0 += xb[t * N_] * Wa[512 + t];
  float e = (a0 + a1) + (a2 + a3);

  __shared__ float red[4];
  float m = e;
  for (int off = 32; off > 0; off >>= 1) m = fmaxf(m, __shfl_xor(m, off));
  int wid = n >> 6;
  if ((n & 63) == 0) red[wid] = m;
  __syncthreads();
  m = fmaxf(fmaxf(red[0], red[1]), fmaxf(red[2], red[3]));
  float ex = __expf(e - m);
  float s = ex;
  for (int off = 32; off > 0; off >>= 1) s += __shfl_xor(s, off);
  __syncthreads();
  if ((n & 63) == 0) red[wid] = s;
  __syncthreads();
  s = (red[0] + red[1]) + (red[2] + red[3]);
  alpha[b * N_ + n] = ex / s;
}

// ---------------- K2: X_tilde = alpha (broadcast over t) * X   (exact fp32)
__global__ __launch_bounds__(256) void k2_xtilde(const float4* __restrict__ X4,
                                                 const float* __restrict__ alpha,
                                                 float4* __restrict__ out4) {
  int i = blockIdx.x * 256 + threadIdx.x;  // over B*T*64 float4s
  if (i < B_ * T_ * 64) {
    int n4 = i & 63;
    int bt = i >> 6;
    int b = bt / T_;
    const float4* A4 = (const float4*)alpha;
    float4 x = X4[i], al = A4[b * 64 + n4];
    float4 r;
    r.x = x.x * al.x; r.y = x.y * al.y; r.z = x.z * al.z; r.w = x.w * al.w;
    out4[i] = r;
  }
}

// ---------------- K3: XW = X_tilde @ W_lstm + b_lstm  -> f16 (32640 x 1024)
#define LDA 40  // f16 row stride in LDS (16B-aligned rows, bank-spread)
__global__ __launch_bounds__(256, 2) void k3_gemm(const float* __restrict__ A,
                                                  const f16* __restrict__ Bt,
                                                  const float* __restrict__ bias,
                                                  f16* __restrict__ Cw) {
  __shared__ f16 As[128 * LDA];
  __shared__ f16 Bs[128 * LDA];
  int tid = threadIdx.x;
  int mt = blockIdx.x;  // 0..254
  int nt = blockIdx.y;  // 0..7
  int lane = tid & 63, wid = tid >> 6;
  int wm = (wid >> 1) * 64, wn = (wid & 1) * 64;
  f32x4 acc[4][4] = {};

  for (int k0 = 0; k0 < 256; k0 += 32) {
    __syncthreads();
#pragma unroll
    for (int it = 0; it < 4; ++it) {  // A: 128 rows x 32 f32 -> f16
      int idx = tid + it * 256;
      int r = idx >> 3, q = idx & 7;
      float4 v = *(const float4*)(A + (mt * 128 + r) * 256 + k0 + q * 4);
      f16x2 p0, p1;
      p0.x = (f16)v.x; p0.y = (f16)v.y; p1.x = (f16)v.z; p1.y = (f16)v.w;
      uint2 w;
      w.x = __builtin_bit_cast(uint32_t, p0);
      w.y = __builtin_bit_cast(uint32_t, p1);
      *(uint2*)(&As[r * LDA + q * 4]) = w;
    }
#pragma unroll
    for (int it = 0; it < 2; ++it) {  // B (already transposed): 128 rows x 32 f16
      int idx = tid + it * 256;
      int r = idx >> 2, q = idx & 3;
      uint4 v = *(const uint4*)(Bt + (nt * 128 + r) * 256 + k0 + q * 8);
      *(uint4*)(&Bs[r * LDA + q * 8]) = v;
    }
    __syncthreads();
    int kb = (lane >> 4) * 8;
    f16x8 af[4], bf[4];
#pragma unroll
    for (int i = 0; i < 4; ++i)
      af[i] = *(const f16x8*)(&As[(wm + i * 16 + (lane & 15)) * LDA + kb]);
#pragma unroll
    for (int j = 0; j < 4; ++j)
      bf[j] = *(const f16x8*)(&Bs[(wn + j * 16 + (lane & 15)) * LDA + kb]);
#pragma unroll
    for (int i = 0; i < 4; ++i)
#pragma unroll
      for (int j = 0; j < 4; ++j)
        acc[i][j] = __builtin_amdgcn_mfma_f32_16x16x32_f16(af[i], bf[j], acc[i][j], 0, 0, 0);
  }
  int colL = wn + (lane & 15);
  int rowB = wm + (lane >> 4) * 4;
#pragma unroll
  for (int j = 0; j < 4; ++j) {
    int ng = nt * 128 + colL + j * 16;
    float bv = bias[ng];
#pragma unroll
    for (int i = 0; i < 4; ++i)
#pragma unroll
      for (int r = 0; r < 4; ++r) {
        int mg = mt * 128 + rowB + i * 16 + r;
        Cw[mg * 1024 + ng] = (f16)(acc[i][j][r] + bv);
      }
  }
}

// ---------------- K4: sequential LSTM recurrence, one block per batch.
// U in f16: k-pairs [0,92) in VGPRs (2 cols/thread, 184 regs), [92,128) in LDS.
// amdgpu_waves_per_eu(2,2): round 1/2 showed the allocator targets 4 waves/EU
// (128-VGPR cap) by default and spills the U array to scratch (6024 cyc/step,
// all L2 reload). LDS (148.5 KB) limits us to 1 block/CU = 2 waves/EU anyway,
// so pinning min=max=2 forces the 256-VGPR budget the U array needs.
__global__ __launch_bounds__(512)
__attribute__((amdgpu_waves_per_eu(2, 2)))
void k4_recur(const float* __restrict__ X,
              const uint32_t* __restrict__ u_packed,
              const uint32_t* __restrict__ xw2,
              float* __restrict__ Xenc) {
  __shared__ uint32_t u_lds[LP_][1024];  // 144 KB
  __shared__ f16 h_lds[256];             // 512 B
  __shared__ float z_lds[1024];          // 4 KB
  int tid = threadIdx.x, b = blockIdx.x;

  uint32_t ur0[RP_], ur1[RP_];
  const uint2* up2 = (const uint2*)u_packed;
#pragma unroll
  for (int p = 0; p < RP_; ++p) {
    uint2 v = up2[p * 512 + tid];
    ur0[p] = v.x;
    ur1[p] = v.y;
  }
  {
    const uint4* src = (const uint4*)(u_packed + RP_ * 1024);
    uint4* dst = (uint4*)&u_lds[0][0];
    for (int i = tid; i < LP_ * 1024 / 4; i += 512) dst[i] = src[i];
  }
  float x00 = X[b * (T_ * N_)];
  float c_st = x00;
  if (tid < 256) h_lds[tid] = (f16)x00;
  __syncthreads();

  const uint32_t* xwb = xw2 + (size_t)b * T_ * 512;
  float* encb = Xenc + (size_t)b * T_ * N_;
  const uint4* h4 = (const uint4*)h_lds;

  uint32_t xwv = xwb[tid];
  for (int t = 0; t < T_; ++t) {
    uint32_t xw_nxt = 0;
    if (t + 1 < T_) xw_nxt = xwb[(t + 1) * 512 + tid];

    float z0a, z1a;
    {
      f16x2 xp = __builtin_bit_cast(f16x2, xwv);
      z0a = (float)xp.x;
      z1a = (float)xp.y;
    }
    float z0b = 0.f, z1b = 0.f;
#pragma unroll
    for (int q = 0; q < RP_ / 4; ++q) {  // register part: k-pairs 0..91
      uint4 hh = h4[q];
      z0a = fdot2(hh.x, ur0[4 * q + 0], z0a); z1a = fdot2(hh.x, ur1[4 * q + 0], z1a);
      z0b = fdot2(hh.y, ur0[4 * q + 1], z0b); z1b = fdot2(hh.y, ur1[4 * q + 1], z1b);
      z0a = fdot2(hh.z, ur0[4 * q + 2], z0a); z1a = fdot2(hh.z, ur1[4 * q + 2], z1a);
      z0b = fdot2(hh.w, ur0[4 * q + 3], z0b); z1b = fdot2(hh.w, ur1[4 * q + 3], z1b);
    }
#pragma unroll
    for (int q = RP_ / 4; q < 32; ++q) {  // LDS part: k-pairs 92..127
      uint4 hh = h4[q];
      uint32_t hw[4] = {hh.x, hh.y, hh.z, hh.w};
#pragma unroll
      for (int r = 0; r < 4; ++r) {
        int p = 4 * q + r - RP_;
        uint2 uu = *(const uint2*)&u_lds[p][2 * tid];
        if (r & 1) { z0b = fdot2(hw[r], uu.x, z0b); z1b = fdot2(hw[r], uu.y, z1b); }
        else       { z0a = fdot2(hw[r], uu.x, z0a); z1a = fdot2(hw[r], uu.y, z1a); }
      }
    }
    float2 zz;
    zz.x = z0a + z0b;
    zz.y = z1a + z1b;
    *(float2*)&z_lds[2 * tid] = zz;
    __syncthreads();
    if (tid < 256) {
      float zi = z_lds[tid], zf = z_lds[256 + tid];
      float zg = z_lds[512 + tid], zo = z_lds[768 + tid];
      float ig = 1.f / (1.f + __expf(-zi));
      float fg = 1.f / (1.f + __expf(-zf));
      float gg = 1.f - 2.f / (1.f + __expf(2.f * zg));
      float og = 1.f / (1.f + __expf(-zo));
      c_st = fg * c_st + ig * gg;
      float hv = og * (1.f - 2.f / (1.f + __expf(2.f * c_st)));
      encb[t * 256 + tid] = hv;
      h_lds[tid] = (f16)hv;
    }
    __syncthreads();
    xwv = xw_nxt;
  }
}

extern "C" void kernel_launch(void* const* d_in, const int* in_sizes, int n_in,
                              void* d_out, int out_size, void* d_ws, size_t ws_size,
                              hipStream_t stream) {
  const float* X = (const float*)d_in[0];
  const float* Wa = (const float*)d_in[1];
  const float* Wl = (const float*)d_in[3];
  const float* Ul = (const float*)d_in[4];
  const float* bl = (const float*)d_in[5];
  float* out = (float*)d_out;
  uint8_t* ws = (uint8_t*)d_ws;

  float* alpha = (float*)ws;                          // 131072 B
  uint32_t* u_packed = (uint32_t*)(ws + 131072);      // 524288 B
  f16* wt = (f16*)(ws + 655360);                      // 524288 B
  f16* xw = (f16*)(ws + 1179648);                     // 66846720 B (~68 MB total)

  k0_pack<<<1024, 256, 0, stream>>>(Wl, Ul, u_packed, wt);
  k1_alpha<<<128, 256, 0, stream>>>(X, Wa, alpha);
  k2_xtilde<<<8160, 256, 0, stream>>>((const float4*)X, alpha, (float4*)out);
  dim3 g3(255, 8);
  k3_gemm<<<g3, 256, 0, stream>>>(out, wt, bl, xw);
  k4_recur<<<128, 512, 0, stream>>>(X, u_packed, (const uint32_t*)xw,
                                    out + 8355840);
}

// Round 4
// 659.311 us; speedup vs baseline: 1.2084x; 1.2084x over previous
//
#include <hip/hip_runtime.h>
#include <hip/hip_bf16.h>
#include <stdint.h>

#define B_ 128
#define T_ 255
#define N_ 256
#define H_ 256

// k4 U split: k-pairs [0,92) in VGPRs (92 regs/thread, 1 col each),
// [92,128) in LDS (9 uint4 rows x 1024 cols = 144 KB)
#define RP_ 92
#define LQ_ 9

typedef _Float16 f16;
typedef _Float16 f16x2 __attribute__((ext_vector_type(2)));
typedef _Float16 f16x8 __attribute__((ext_vector_type(8)));
typedef float f32x4 __attribute__((ext_vector_type(4)));

static __device__ __forceinline__ float fdot2(uint32_t h, uint32_t u, float acc) {
#if __has_builtin(__builtin_amdgcn_fdot2)
  return __builtin_amdgcn_fdot2(__builtin_bit_cast(f16x2, h),
                                __builtin_bit_cast(f16x2, u), acc, false);
#else
  f16x2 a = __builtin_bit_cast(f16x2, h);
  f16x2 b = __builtin_bit_cast(f16x2, u);
  return acc + (float)a.x * (float)b.x + (float)a.y * (float)b.y;
#endif
}

// ---------------- K0: pack W_lstm (transposed) and U_lstm (k-pair packed) to f16
__global__ __launch_bounds__(256) void k0_pack(const float* __restrict__ Wl,
                                               const float* __restrict__ Ul,
                                               uint32_t* __restrict__ u_packed,
                                               f16* __restrict__ wt) {
  int idx = blockIdx.x * 256 + threadIdx.x;
  if (idx < 256 * 1024) {              // wt[n][k] = Wl[k][n]
    int n = idx >> 8, k = idx & 255;
    wt[n * 256 + k] = (f16)Wl[k * 1024 + n];
  }
  if (idx < 128 * 1024) {              // u_packed[p][c] = (U[2p][c], U[2p+1][c])
    int p = idx >> 10, c = idx & 1023;
    f16x2 v;
    v.x = (f16)Ul[(2 * p) * 1024 + c];
    v.y = (f16)Ul[(2 * p + 1) * 1024 + c];
    u_packed[idx] = __builtin_bit_cast(uint32_t, v);
  }
}

// ---------------- K1: alpha[b][n] = softmax_n( sum_t X[b,t,n] * Wa[512+t] )
__global__ __launch_bounds__(256) void k1_alpha(const float* __restrict__ X,
                                                const float* __restrict__ Wa,
                                                float* __restrict__ alpha) {
  int b = blockIdx.x, n = threadIdx.x;
  const float* xb = X + b * (T_ * N_) + n;
  float a0 = 0.f, a1 = 0.f, a2 = 0.f, a3 = 0.f;
  int t = 0;
  for (; t + 4 <= T_; t += 4) {
    a0 += xb[(t + 0) * N_] * Wa[512 + t + 0];
    a1 += xb[(t + 1) * N_] * Wa[512 + t + 1];
    a2 += xb[(t + 2) * N_] * Wa[512 + t + 2];
    a3 += xb[(t + 3) * N_] * Wa[512 + t + 3];
  }
  for (; t < T_; ++t) a0 += xb[t * N_] * Wa[512 + t];
  float e = (a0 + a1) + (a2 + a3);

  __shared__ float red[4];
  float m = e;
  for (int off = 32; off > 0; off >>= 1) m = fmaxf(m, __shfl_xor(m, off));
  int wid = n >> 6;
  if ((n & 63) == 0) red[wid] = m;
  __syncthreads();
  m = fmaxf(fmaxf(red[0], red[1]), fmaxf(red[2], red[3]));
  float ex = __expf(e - m);
  float s = ex;
  for (int off = 32; off > 0; off >>= 1) s += __shfl_xor(s, off);
  __syncthreads();
  if ((n & 63) == 0) red[wid] = s;
  __syncthreads();
  s = (red[0] + red[1]) + (red[2] + red[3]);
  alpha[b * N_ + n] = ex / s;
}

// ---------------- K2: X_tilde = alpha (broadcast over t) * X   (exact fp32)
__global__ __launch_bounds__(256) void k2_xtilde(const float4* __restrict__ X4,
                                                 const float* __restrict__ alpha,
                                                 float4* __restrict__ out4) {
  int i = blockIdx.x * 256 + threadIdx.x;  // over B*T*64 float4s
  if (i < B_ * T_ * 64) {
    int n4 = i & 63;
    int bt = i >> 6;
    int b = bt / T_;
    const float4* A4 = (const float4*)alpha;
    float4 x = X4[i], al = A4[b * 64 + n4];
    float4 r;
    r.x = x.x * al.x; r.y = x.y * al.y; r.z = x.z * al.z; r.w = x.w * al.w;
    out4[i] = r;
  }
}

// ---------------- K3: XW = X_tilde @ W_lstm + b_lstm  -> f16 (32640 x 1024)
#define LDA 40  // f16 row stride in LDS (16B-aligned rows, bank-spread)
__global__ __launch_bounds__(256, 2) void k3_gemm(const float* __restrict__ A,
                                                  const f16* __restrict__ Bt,
                                                  const float* __restrict__ bias,
                                                  f16* __restrict__ Cw) {
  __shared__ f16 As[128 * LDA];
  __shared__ f16 Bs[128 * LDA];
  int tid = threadIdx.x;
  int mt = blockIdx.x;  // 0..254
  int nt = blockIdx.y;  // 0..7
  int lane = tid & 63, wid = tid >> 6;
  int wm = (wid >> 1) * 64, wn = (wid & 1) * 64;
  f32x4 acc[4][4] = {};

  for (int k0 = 0; k0 < 256; k0 += 32) {
    __syncthreads();
#pragma unroll
    for (int it = 0; it < 4; ++it) {  // A: 128 rows x 32 f32 -> f16
      int idx = tid + it * 256;
      int r = idx >> 3, q = idx & 7;
      float4 v = *(const float4*)(A + (mt * 128 + r) * 256 + k0 + q * 4);
      f16x2 p0, p1;
      p0.x = (f16)v.x; p0.y = (f16)v.y; p1.x = (f16)v.z; p1.y = (f16)v.w;
      uint2 w;
      w.x = __builtin_bit_cast(uint32_t, p0);
      w.y = __builtin_bit_cast(uint32_t, p1);
      *(uint2*)(&As[r * LDA + q * 4]) = w;
    }
#pragma unroll
    for (int it = 0; it < 2; ++it) {  // B (already transposed): 128 rows x 32 f16
      int idx = tid + it * 256;
      int r = idx >> 2, q = idx & 3;
      uint4 v = *(const uint4*)(Bt + (nt * 128 + r) * 256 + k0 + q * 8);
      *(uint4*)(&Bs[r * LDA + q * 8]) = v;
    }
    __syncthreads();
    int kb = (lane >> 4) * 8;
    f16x8 af[4], bf[4];
#pragma unroll
    for (int i = 0; i < 4; ++i)
      af[i] = *(const f16x8*)(&As[(wm + i * 16 + (lane & 15)) * LDA + kb]);
#pragma unroll
    for (int j = 0; j < 4; ++j)
      bf[j] = *(const f16x8*)(&Bs[(wn + j * 16 + (lane & 15)) * LDA + kb]);
#pragma unroll
    for (int i = 0; i < 4; ++i)
#pragma unroll
      for (int j = 0; j < 4; ++j)
        acc[i][j] = __builtin_amdgcn_mfma_f32_16x16x32_f16(af[i], bf[j], acc[i][j], 0, 0, 0);
  }
  int colL = wn + (lane & 15);
  int rowB = wm + (lane >> 4) * 4;
#pragma unroll
  for (int j = 0; j < 4; ++j) {
    int ng = nt * 128 + colL + j * 16;
    float bv = bias[ng];
#pragma unroll
    for (int i = 0; i < 4; ++i)
#pragma unroll
      for (int r = 0; r < 4; ++r) {
        int mg = mt * 128 + rowB + i * 16 + r;
        Cw[mg * 1024 + ng] = (f16)(acc[i][j][r] + bv);
      }
  }
}

// ---------------- K4: sequential LSTM recurrence, one block per batch.
// 1024 threads, ONE z-column per thread. U k-pairs [0,92) live in 92
// VGPRs/thread; pairs [92,128) in LDS. Register demand ~115 fits UNDER the
// 128-VGPR cap the allocator insists on (rounds 1-3: every attribute attempt
// to raise it failed; at 128 the compiler rematerialized the 184-reg U array
// from global every step -> 6000 cyc/step of L2 reload). This layout makes
// remat structurally unnecessary.
__global__ __launch_bounds__(1024) void k4_recur(const float* __restrict__ X,
                                                 const uint32_t* __restrict__ u_packed,
                                                 const f16* __restrict__ xwf,
                                                 float* __restrict__ Xenc) {
  __shared__ __align__(16) uint32_t u_lds[LQ_ * 1024 * 4];  // 144 KB
  __shared__ __align__(16) f16 h_lds[256];                  // 512 B
  __shared__ __align__(16) float z_lds[1024];               // 4 KB
  int tid = threadIdx.x, b = blockIdx.x;

  uint32_t ur[RP_];
#pragma unroll
  for (int p = 0; p < RP_; ++p) ur[p] = u_packed[p * 1024 + tid];

  {  // u_lds[q][c] = pairs (92+4q .. 92+4q+3) at col c, uint4-interleaved
    uint4* dst = (uint4*)u_lds;
#pragma unroll
    for (int q = 0; q < LQ_; ++q) {
      int base = (RP_ + 4 * q) * 1024 + tid;
      uint4 v;
      v.x = u_packed[base];
      v.y = u_packed[base + 1024];
      v.z = u_packed[base + 2048];
      v.w = u_packed[base + 3072];
      dst[q * 1024 + tid] = v;
    }
  }
  float x00 = X[b * (T_ * N_)];
  float c_st = x00;
  if (tid < 256) h_lds[tid] = (f16)x00;
  __syncthreads();

  const f16* xwb = xwf + (size_t)b * T_ * 1024;
  float* encb = Xenc + (size_t)b * T_ * N_;
  const uint4* h4 = (const uint4*)h_lds;
  const uint4* u4 = (const uint4*)u_lds;

  float xwv = (float)xwb[tid];
  for (int t = 0; t < T_; ++t) {
    float xw_nxt = 0.f;
    if (t + 1 < T_) xw_nxt = (float)xwb[(t + 1) * 1024 + tid];

    float za = xwv, zb = 0.f;
#pragma unroll
    for (int q = 0; q < RP_ / 4; ++q) {  // register part: pairs 0..91
      uint4 hh = h4[q];
      za = fdot2(hh.x, ur[4 * q + 0], za);
      zb = fdot2(hh.y, ur[4 * q + 1], zb);
      za = fdot2(hh.z, ur[4 * q + 2], za);
      zb = fdot2(hh.w, ur[4 * q + 3], zb);
    }
#pragma unroll
    for (int q = 0; q < LQ_; ++q) {      // LDS part: pairs 92..127
      uint4 hh = h4[RP_ / 4 + q];
      uint4 uu = u4[q * 1024 + tid];
      za = fdot2(hh.x, uu.x, za);
      zb = fdot2(hh.y, uu.y, zb);
      za = fdot2(hh.z, uu.z, za);
      zb = fdot2(hh.w, uu.w, zb);
    }
    z_lds[tid] = za + zb;
    __syncthreads();
    if (tid < 256) {
      float zi = z_lds[tid], zf = z_lds[256 + tid];
      float zg = z_lds[512 + tid], zo = z_lds[768 + tid];
      float ig = 1.f / (1.f + __expf(-zi));
      float fg = 1.f / (1.f + __expf(-zf));
      float gg = 1.f - 2.f / (1.f + __expf(2.f * zg));
      float og = 1.f / (1.f + __expf(-zo));
      c_st = fg * c_st + ig * gg;
      float hv = og * (1.f - 2.f / (1.f + __expf(2.f * c_st)));
      encb[t * 256 + tid] = hv;
      h_lds[tid] = (f16)hv;
    }
    __syncthreads();
    xwv = xw_nxt;
  }
}

extern "C" void kernel_launch(void* const* d_in, const int* in_sizes, int n_in,
                              void* d_out, int out_size, void* d_ws, size_t ws_size,
                              hipStream_t stream) {
  const float* X = (const float*)d_in[0];
  const float* Wa = (const float*)d_in[1];
  const float* Wl = (const float*)d_in[3];
  const float* Ul = (const float*)d_in[4];
  const float* bl = (const float*)d_in[5];
  float* out = (float*)d_out;
  uint8_t* ws = (uint8_t*)d_ws;

  float* alpha = (float*)ws;                          // 131072 B
  uint32_t* u_packed = (uint32_t*)(ws + 131072);      // 524288 B
  f16* wt = (f16*)(ws + 655360);                      // 524288 B
  f16* xw = (f16*)(ws + 1179648);                     // 66846720 B (~68 MB total)

  k0_pack<<<1024, 256, 0, stream>>>(Wl, Ul, u_packed, wt);
  k1_alpha<<<128, 256, 0, stream>>>(X, Wa, alpha);
  k2_xtilde<<<8160, 256, 0, stream>>>((const float4*)X, alpha, (float4*)out);
  dim3 g3(255, 8);
  k3_gemm<<<g3, 256, 0, stream>>>(out, wt, bl, xw);
  k4_recur<<<128, 1024, 0, stream>>>(X, u_packed, xw, out + 8355840);
}